// Round 1
// baseline (2087.783 us; speedup 1.0000x reference)
//
#include <hip/hip_runtime.h>

#define DEV __device__ __forceinline__

DEV float4 ld4(const float* p){ return *reinterpret_cast<const float4*>(p); }
DEV void st4(float* p, float4 v){ *reinterpret_cast<float4*>(p) = v; }
DEV float4 relu4(float4 v){ return make_float4(fmaxf(v.x,0.f),fmaxf(v.y,0.f),fmaxf(v.z,0.f),fmaxf(v.w,0.f)); }
DEV void fma4(float4& a, float s, const float4& w){
    a.x = fmaf(s,w.x,a.x); a.y = fmaf(s,w.y,a.y); a.z = fmaf(s,w.z,a.z); a.w = fmaf(s,w.w,a.w);
}

// ---------------- fill rows with a bias pattern ----------------
template<int COUT>
__global__ __launch_bounds__(256)
void fill_bias(float* __restrict__ Y, const float* __restrict__ b, int n_rows){
    constexpr int Q = COUT/4;
    long i = (long)blockIdx.x*256 + threadIdx.x;
    if (i >= (long)n_rows*Q) return;
    int q = (int)(i % Q);   // Q is a power of two
    reinterpret_cast<float4*>(Y)[i] = reinterpret_cast<const float4*>(b)[q];
}

// ---------------- inverse kernel-map build ----------------
__global__ __launch_bounds__(256)
void inv_init(int* __restrict__ inv, long n){
    long i = (long)blockIdx.x*256 + threadIdx.x;
    if (i < n) inv[i] = -1;
}

__global__ __launch_bounds__(256)
void inv_build(const int* __restrict__ in3, const int* __restrict__ out3,
               int* __restrict__ inv, int M, int n_out){
    int k = blockIdx.x;
    long m = (long)blockIdx.y*256 + threadIdx.x;
    if (m >= M) return;
    long e = (long)k*M + m;
    int o = out3[e];
    if (o != n_out) inv[(long)k*n_out + o] = in3[e];  // o unique within offset k
}

// ---------------- conv1: scatter with atomics ----------------
// block: 256 threads = 128 pair-slots x 2 channel-groups; 256 pairs per block
__global__ __launch_bounds__(256)
void conv1_scatter(const float* __restrict__ xF, const float* __restrict__ ctxF,
                   const float* __restrict__ W1,
                   const int* __restrict__ in1, const int* __restrict__ out1,
                   float* __restrict__ Y, int M1, int n_out)
{
    const int k = blockIdx.x;
    const long base = (long)blockIdx.y * 256;
    const int* __restrict__ inL  = in1  + (long)k*M1;
    const int* __restrict__ outL = out1 + (long)k*M1;
    if (outL[base] == n_out) return;   // pads are a contiguous tail
    __shared__ float Wl[128*64];
    {
        const float4* __restrict__ src = reinterpret_cast<const float4*>(W1) + (long)k*(128*64/4);
        float4* dst = reinterpret_cast<float4*>(Wl);
        #pragma unroll
        for (int i = 0; i < 8; ++i) dst[threadIdx.x + 256*i] = src[threadIdx.x + 256*i];
    }
    __syncthreads();
    const int cg = threadIdx.x & 1;
    const int pq = threadIdx.x >> 1;
    const int cbase = cg*32;
    long m0 = base + pq, m1 = base + 128 + pq;
    int i0=0,i1=0,o0=0,o1=0; bool v0=false,v1=false;
    if (m0 < M1){ int o=outL[m0]; if (o!=n_out){ v0=true; o0=o; i0=inL[m0]; } }
    if (m1 < M1){ int o=outL[m1]; if (o!=n_out){ v1=true; o1=o; i1=inL[m1]; } }
    float4 acc0[8], acc1[8];
    #pragma unroll
    for (int q=0;q<8;++q){ acc0[q]=make_float4(0,0,0,0); acc1[q]=make_float4(0,0,0,0); }
    #pragma unroll 1
    for (int half=0; half<2; ++half){
        const float* __restrict__ S = half ? ctxF : xF;
        const float* __restrict__ R0 = S + (long)i0*64;
        const float* __restrict__ R1 = S + (long)i1*64;
        const float* __restrict__ Wh = Wl + half*64*64 + cbase;
        #pragma unroll 4
        for (int c0=0; c0<64; c0+=4){
            float4 x0 = v0 ? ld4(R0+c0) : make_float4(0,0,0,0);
            float4 x1 = v1 ? ld4(R1+c0) : make_float4(0,0,0,0);
            #pragma unroll
            for (int i=0;i<4;++i){
                const float4* wr = reinterpret_cast<const float4*>(Wh + (c0+i)*64);
                float s0 = reinterpret_cast<const float*>(&x0)[i];
                float s1 = reinterpret_cast<const float*>(&x1)[i];
                #pragma unroll
                for (int q=0;q<8;++q){
                    float4 w = wr[q];
                    fma4(acc0[q], s0, w);
                    fma4(acc1[q], s1, w);
                }
            }
        }
    }
    if (v0){
        float* yp = Y + (long)o0*64 + cbase;
        #pragma unroll
        for (int q=0;q<8;++q){
            atomicAdd(yp+4*q+0, acc0[q].x); atomicAdd(yp+4*q+1, acc0[q].y);
            atomicAdd(yp+4*q+2, acc0[q].z); atomicAdd(yp+4*q+3, acc0[q].w);
        }
    }
    if (v1){
        float* yp = Y + (long)o1*64 + cbase;
        #pragma unroll
        for (int q=0;q<8;++q){
            atomicAdd(yp+4*q+0, acc1[q].x); atomicAdd(yp+4*q+1, acc1[q].y);
            atomicAdd(yp+4*q+2, acc1[q].z); atomicAdd(yp+4*q+3, acc1[q].w);
        }
    }
}

// ---------------- 27-offset sparse conv, gather form ----------------
// block: 128 threads, 2 rows/thread -> 256 output rows per block
template<int CIN, int COUT, bool RELU_OUT, bool ADD_SRC>
__global__ __launch_bounds__(128)
void gather27(const float* __restrict__ X, int x_stride,
              const float* __restrict__ W,
              const int* __restrict__ inv, const float* __restrict__ bias,
              const float* __restrict__ SRC,
              float* __restrict__ Y, int y_stride, int n_out)
{
    constexpr int Q = COUT/4;
    const long base = (long)blockIdx.x * 256;
    const int j0 = (int)(base + threadIdx.x);
    const int j1 = j0 + 128;
    const bool a0 = j0 < n_out, a1 = j1 < n_out;
    __shared__ float Wl[CIN*COUT];
    float4 acc0[Q], acc1[Q];
    #pragma unroll
    for (int q=0;q<Q;++q){ float4 b4 = ld4(bias+4*q); acc0[q]=b4; acc1[q]=b4; }
    for (int k=0;k<27;++k){
        __syncthreads();
        for (int i=threadIdx.x; i<CIN*COUT/4; i+=128)
            reinterpret_cast<float4*>(Wl)[i] =
                reinterpret_cast<const float4*>(W)[(long)k*(CIN*COUT/4)+i];
        __syncthreads();
        const long kb = (long)k*n_out;
        int b0 = a0 ? inv[kb + j0] : -1;
        int b1 = a1 ? inv[kb + j1] : -1;
        const float* R0 = X + (long)b0*x_stride;
        const float* R1 = X + (long)b1*x_stride;
        const bool g0 = b0 >= 0, g1 = b1 >= 0;
        #pragma unroll 4
        for (int c0=0;c0<CIN;c0+=4){
            float4 x0 = g0 ? ld4(R0+c0) : make_float4(0,0,0,0);
            float4 x1 = g1 ? ld4(R1+c0) : make_float4(0,0,0,0);
            #pragma unroll
            for (int i=0;i<4;++i){
                const float4* wr = reinterpret_cast<const float4*>(Wl + (c0+i)*COUT);
                float s0 = reinterpret_cast<const float*>(&x0)[i];
                float s1 = reinterpret_cast<const float*>(&x1)[i];
                #pragma unroll
                for (int q=0;q<Q;++q){
                    float4 w = wr[q];
                    fma4(acc0[q], s0, w);
                    fma4(acc1[q], s1, w);
                }
            }
        }
    }
    if (a0){
        float* yp = Y + (long)j0*y_stride;
        #pragma unroll
        for (int q=0;q<Q;++q){
            float4 v = acc0[q];
            if constexpr (ADD_SRC){
                float4 s = ld4(SRC + (long)j0*64 + 4*q);
                v.x+=s.x; v.y+=s.y; v.z+=s.z; v.w+=s.w;
            }
            if constexpr (RELU_OUT) v = relu4(v);
            st4(yp + 4*q, v);
        }
    }
    if (a1){
        float* yp = Y + (long)j1*y_stride;
        #pragma unroll
        for (int q=0;q<Q;++q){
            float4 v = acc1[q];
            if constexpr (ADD_SRC){
                float4 s = ld4(SRC + (long)j1*64 + 4*q);
                v.x+=s.x; v.y+=s.y; v.z+=s.z; v.w+=s.w;
            }
            if constexpr (RELU_OUT) v = relu4(v);
            st4(yp + 4*q, v);
        }
    }
}

// ---------------- dense 1x1: D = relu(A @ Wr10 + br10) ----------------
__global__ __launch_bounds__(256)
void dense_t1(const float* __restrict__ A, const float* __restrict__ Wr10,
              const float* __restrict__ br10, float* __restrict__ D, int n_out)
{
    __shared__ float Wl[64*16];
    for (int i=threadIdx.x; i<256; i+=256)
        reinterpret_cast<float4*>(Wl)[i] = reinterpret_cast<const float4*>(Wr10)[i];
    __syncthreads();
    int j = blockIdx.x*256 + threadIdx.x;
    if (j >= n_out) return;
    const float* a = A + (long)j*64;
    float4 d[4];
    #pragma unroll
    for (int q=0;q<4;++q) d[q] = ld4(br10+4*q);
    #pragma unroll 4
    for (int c0=0;c0<64;c0+=4){
        float4 x = ld4(a+c0);
        #pragma unroll
        for (int i=0;i<4;++i){
            float s = reinterpret_cast<const float*>(&x)[i];
            const float4* wr = reinterpret_cast<const float4*>(Wl + (c0+i)*16);
            #pragma unroll
            for (int q=0;q<4;++q) fma4(d[q], s, wr[q]);
        }
    }
    float* dp = D + (long)j*64;    // D lives in C[:,32:48]; row stride 64
    #pragma unroll
    for (int q=0;q<4;++q) st4(dp+4*q, relu4(d[q]));
}

// ---------------- dense 1x1: C[:,32:64] = E @ Wr12 + br12 + A[:,32:64] ----------------
__global__ __launch_bounds__(256)
void path1_k(const float* __restrict__ E, const float* __restrict__ Wr12,
             const float* __restrict__ br12, const float* __restrict__ A,
             float* __restrict__ C, int n_out)
{
    __shared__ float Wl[16*32];
    for (int i=threadIdx.x; i<128; i+=256)
        reinterpret_cast<float4*>(Wl)[i] = reinterpret_cast<const float4*>(Wr12)[i];
    __syncthreads();
    int j = blockIdx.x*256 + threadIdx.x;
    if (j >= n_out) return;
    float e[16];
    #pragma unroll
    for (int q=0;q<4;++q) *reinterpret_cast<float4*>(e+4*q) = ld4(E + (long)j*16 + 4*q);
    float4 acc[8];
    #pragma unroll
    for (int q=0;q<8;++q){
        float4 b = ld4(br12+4*q);
        float4 s = ld4(A + (long)j*64 + 32 + 4*q);
        acc[q] = make_float4(b.x+s.x, b.y+s.y, b.z+s.z, b.w+s.w);
    }
    #pragma unroll
    for (int c=0;c<16;++c){
        float s = e[c];
        const float4* wr = reinterpret_cast<const float4*>(Wl + c*32);
        #pragma unroll
        for (int q=0;q<8;++q) fma4(acc[q], s, wr[q]);
    }
    float* cp = C + (long)j*64 + 32;
    #pragma unroll
    for (int q=0;q<8;++q) st4(cp+4*q, acc[q]);
}

extern "C" void kernel_launch(void* const* d_in, const int* in_sizes, int n_in_cnt,
                              void* d_out, int out_size, void* d_ws, size_t ws_size,
                              hipStream_t stream)
{
    const float* xF   = (const float*)d_in[0];
    const float* ctxF = (const float*)d_in[1];
    const float* W1   = (const float*)d_in[2];
    const float* b1   = (const float*)d_in[3];
    const float* Wr00 = (const float*)d_in[4];
    const float* br00 = (const float*)d_in[5];
    const float* Wr01 = (const float*)d_in[6];
    const float* br01 = (const float*)d_in[7];
    const float* Wr10 = (const float*)d_in[8];
    const float* br10 = (const float*)d_in[9];
    const float* Wr11 = (const float*)d_in[10];
    const float* br11 = (const float*)d_in[11];
    const float* Wr12 = (const float*)d_in[12];
    const float* br12 = (const float*)d_in[13];
    const float* W2   = (const float*)d_in[14];
    const float* b2   = (const float*)d_in[15];
    const int* in1  = (const int*)d_in[16];
    const int* out1 = (const int*)d_in[17];
    const int* in3  = (const int*)d_in[18];
    const int* out3 = (const int*)d_in[19];

    const int n_out = out_size / 8;          // CL = 8
    const int M1 = in_sizes[16] / 8;
    const int M3 = in_sizes[18] / 27;

    float* ws = (float*)d_ws;
    float* A    = ws;                                   // [n_out][64]  h0
    float* B    = ws + (size_t)64*n_out;                // [n_out][16]  relu(sconv00)
    float* C    = ws + (size_t)80*n_out;                // [n_out][64]  concat+residual
    int*   inv3 = (int*)(ws + (size_t)144*n_out);       // [27][n_out]
    float* E    = B;                                    // alias: B dead before E written
    float* D    = C + 32;                               // t1 in C[:,32:48], stride 64
    float* OUT  = (float*)d_out;

    auto cdiv = [](long a, long b){ return (int)((a + b - 1)/b); };

    // inverse kernel map
    inv_init<<<cdiv((long)27*n_out,256),256,0,stream>>>(inv3, (long)27*n_out);
    inv_build<<<dim3(27,cdiv(M3,256)),256,0,stream>>>(in3, out3, inv3, M3, n_out);

    // conv1: A = b1 rows, then scatter-add
    fill_bias<64><<<cdiv((long)n_out*16,256),256,0,stream>>>(A, b1, n_out);
    conv1_scatter<<<dim3(8,cdiv(M1,256)),256,0,stream>>>(xF, ctxF, W1, in1, out1, A, M1, n_out);

    // B = relu(sconv(A, Wr00) + br00)
    gather27<64,16,true,false><<<cdiv(n_out,256),128,0,stream>>>(A, 64, Wr00, inv3, br00, nullptr, B, 16, n_out);
    // D = relu(A @ Wr10 + br10)   (stored in C[:,32:48])
    dense_t1<<<cdiv(n_out,256),256,0,stream>>>(A, Wr10, br10, D, n_out);
    // C[:,0:32] = sconv(B, Wr01) + br01 + A[:,0:32]
    gather27<16,32,false,true><<<cdiv(n_out,256),128,0,stream>>>(B, 16, Wr01, inv3, br01, A, C, 64, n_out);
    // E = relu(sconv(D, Wr11) + br11)
    gather27<16,16,true,false><<<cdiv(n_out,256),128,0,stream>>>(D, 64, Wr11, inv3, br11, nullptr, E, 16, n_out);
    // C[:,32:64] = E @ Wr12 + br12 + A[:,32:64]   (overwrites the D slot, safely after its last read)
    path1_k<<<cdiv(n_out,256),256,0,stream>>>(E, Wr12, br12, A, C, n_out);
    // OUT = sconv(C, W2) + b2
    gather27<64,8,false,false><<<cdiv(n_out,256),128,0,stream>>>(C, 64, W2, inv3, b2, nullptr, OUT, 8, n_out);
}